// Round 7
// baseline (606.657 us; speedup 1.0000x reference)
//
#include <hip/hip_runtime.h>
#include <stdint.h>

#define T_TOK 8192
#define DDIM 1024
#define EEXP 8
#define FDIM 2048
#define GBLK 512   // gate blocks; 16 tokens each

typedef float f32x4 __attribute__((ext_vector_type(4)));
typedef __bf16 bf16x8 __attribute__((ext_vector_type(8)));
typedef unsigned short us8 __attribute__((ext_vector_type(8)));

#define VMCNT(N) asm volatile("s_waitcnt vmcnt(" #N ")" ::: "memory")
#define BAR() __builtin_amdgcn_s_barrier()

__device__ __forceinline__ unsigned short f2bf(float f) {
  union { float f; unsigned int u; } v; v.f = f;
  unsigned int r = (v.u + 0x7fffu + ((v.u >> 16) & 1u)) >> 16;
  return (unsigned short)r;
}

__device__ __forceinline__ void async_cp16(const void* g, void* l) {
  __builtin_amdgcn_global_load_lds(
      (const __attribute__((address_space(1))) unsigned int*)g,
      (__attribute__((address_space(3))) unsigned int*)l, 16, 0, 0);
}

// ---------------- merged vectorized transpose-cast of w1/w3/w2 ----------------
__global__ __launch_bounds__(256) void transpose_cast3_kernel(
    const float* __restrict__ w1, const float* __restrict__ w3, const float* __restrict__ w2,
    unsigned short* __restrict__ w1t, unsigned short* __restrict__ w3t,
    unsigned short* __restrict__ w2t) {
  __shared__ float tile[64][65];
  const int z = blockIdx.z;
  const float* in;
  unsigned short* out;
  int R, C;
  if (z < 16) {
    R = DDIM; C = FDIM;
    const float* s = (z < 8) ? w1 : w3;
    unsigned short* o = (z < 8) ? w1t : w3t;
    in = s + (size_t)(z & 7) * R * C;
    out = o + (size_t)(z & 7) * R * C;
  } else {
    R = FDIM; C = DDIM;
    in = w2 + (size_t)(z & 7) * R * C;
    out = w2t + (size_t)(z & 7) * R * C;
  }
  const int c0 = blockIdx.x * 64;
  const int r0 = blockIdx.y * 64;
  if (c0 >= C || r0 >= R) return;
  const int t = threadIdx.x;
  const int pr = t >> 4;
  const int pc = (t & 15) * 4;
#pragma unroll
  for (int i = 0; i < 4; i++) {
    float4 v = *(const float4*)&in[(size_t)(r0 + pr + i * 16) * C + c0 + pc];
    tile[pr + i * 16][pc + 0] = v.x;
    tile[pr + i * 16][pc + 1] = v.y;
    tile[pr + i * 16][pc + 2] = v.z;
    tile[pr + i * 16][pc + 3] = v.w;
  }
  __syncthreads();
  const int qr = (t & 7) * 8;
  const int qc = t >> 3;
#pragma unroll
  for (int i = 0; i < 2; i++) {
    int cc = qc + i * 32;
    us8 o;
#pragma unroll
    for (int j = 0; j < 8; j++) o[j] = f2bf(tile[qr + j][cc]);
    *(us8*)&out[(size_t)(c0 + cc) * R + r0 + qr] = o;
  }
}

// ---------------- gating + fused x cast: NO global atomics ----------------
__global__ __launch_bounds__(256) void gate_kernel(const float* __restrict__ x,
                                                   const float* __restrict__ wg,
                                                   unsigned short* __restrict__ xb,
                                                   int* __restrict__ sel,
                                                   float* __restrict__ prb,
                                                   int* __restrict__ cnt_blk) {
  __shared__ float wgs[8 * 1024];  // [e][d]
  __shared__ int cnt[8];
  const int tid = threadIdx.x;
  if (tid < 8) cnt[tid] = 0;
  for (int i = tid; i < 8192; i += 256) {
    int d = i >> 3, e = i & 7;
    wgs[e * 1024 + d] = wg[i];
  }
  __syncthreads();
  const int lane = tid & 63;
  const int wv = tid >> 6;
#pragma unroll 1
  for (int tt = 0; tt < 4; tt++) {
    const int t = blockIdx.x * 16 + tt * 4 + wv;
    const float4* xp = (const float4*)(x + (size_t)t * 1024);
    float4 xv[4];
#pragma unroll
    for (int it = 0; it < 4; it++) xv[it] = xp[lane + it * 64];
    float acc[8] = {0.f, 0.f, 0.f, 0.f, 0.f, 0.f, 0.f, 0.f};
    ushort4* xbp = (ushort4*)(xb + (size_t)t * 1024);
#pragma unroll
    for (int it = 0; it < 4; it++) {
      const int d = (lane + it * 64) * 4;
      float4 v = xv[it];
      ushort4 o;
      o.x = f2bf(v.x); o.y = f2bf(v.y); o.z = f2bf(v.z); o.w = f2bf(v.w);
      xbp[lane + it * 64] = o;
#pragma unroll
      for (int e = 0; e < 8; e++)
        acc[e] += v.x * wgs[e * 1024 + d] + v.y * wgs[e * 1024 + d + 1] +
                  v.z * wgs[e * 1024 + d + 2] + v.w * wgs[e * 1024 + d + 3];
    }
#pragma unroll
    for (int e = 0; e < 8; e++) {
      acc[e] += __shfl_xor(acc[e], 32);
      acc[e] += __shfl_xor(acc[e], 16);
      acc[e] += __shfl_xor(acc[e], 8);
      acc[e] += __shfl_xor(acc[e], 4);
      acc[e] += __shfl_xor(acc[e], 2);
      acc[e] += __shfl_xor(acc[e], 1);
    }
    if (lane == 0) {
      int i0 = 0; float v0 = acc[0];
#pragma unroll
      for (int e = 1; e < 8; e++) if (acc[e] > v0) { v0 = acc[e]; i0 = e; }
      int i1 = -1; float v1 = -1e30f;
#pragma unroll
      for (int e = 0; e < 8; e++) if (e != i0 && acc[e] > v1) { v1 = acc[e]; i1 = e; }
      float ex = __expf(v1 - v0);
      float inv = 1.0f / (1.0f + ex);
      sel[t * 2] = i0; sel[t * 2 + 1] = i1;
      prb[t * 2] = inv; prb[t * 2 + 1] = ex * inv;
      atomicAdd(&cnt[i0], 1);   // LDS atomics only
      atomicAdd(&cnt[i1], 1);
    }
  }
  __syncthreads();
  if (tid < 8) cnt_blk[blockIdx.x * 8 + tid] = cnt[tid];
}

// ---------------- scan: totals, expert offsets, per-gate-block offsets -------
__global__ __launch_bounds__(64) void scan_kernel(const int* __restrict__ cnt_blk,
                                                  int* __restrict__ hdr,
                                                  int* __restrict__ blk_off) {
  __shared__ int part[64];
  const int i = threadIdx.x;
  const int e = i & 7, chunk = i >> 3;
  const int CPB = GBLK / 8;
  int s = 0;
  for (int b = 0; b < CPB; b++) s += cnt_blk[(chunk * CPB + b) * 8 + e];
  part[i] = s;
  __syncthreads();
  if (i < 8) {
    int tot = 0;
#pragma unroll
    for (int c = 0; c < 8; c++) tot += part[c * 8 + i];
    hdr[i] = tot;
  }
  __syncthreads();
  if (i == 0) {
    int s2 = 0;
    for (int e2 = 0; e2 < 8; e2++) { hdr[16 + e2] = s2; s2 += hdr[e2]; }
    hdr[24] = s2;
  }
  __syncthreads();
  int running = hdr[16 + e];
  for (int c = 0; c < chunk; c++) running += part[c * 8 + e];
  for (int b = 0; b < CPB; b++) {
    int idx = (chunk * CPB + b) * 8 + e;
    blk_off[idx] = running;
    running += cnt_blk[idx];
  }
}

// ---------------- build: ballot-ranked, deterministic, no atomics ------------
__global__ __launch_bounds__(64) void build_kernel(const int* __restrict__ sel,
                                                   const int* __restrict__ blk_off,
                                                   int* __restrict__ rows,
                                                   int* __restrict__ slot_of) {
  const int lane = threadIdx.x;
  const int i = blockIdx.x * 64 + lane;
  const int gb = i >> 5;
  const int e = sel[i];
  unsigned long long m = 0;
#pragma unroll
  for (int ee = 0; ee < 8; ee++) {
    unsigned long long be = __ballot(e == ee);
    if (ee == e) m = be;
  }
  const unsigned long long half =
      (lane < 32) ? 0x00000000FFFFFFFFull : 0xFFFFFFFF00000000ull;
  const unsigned long long below = (1ull << lane) - 1ull;
  const int rank = __popcll(m & half & below);
  const int pos = blk_off[gb * 8 + e] + rank;
  rows[pos] = i >> 1;
  slot_of[i] = pos;
}

// ======== counted-vmcnt GEMMs, 128-row tiles, 2 blocks/CU (decorrelated) =====
// 256 threads, 64 KiB LDS -> 2 independent blocks co-resident per CU: when one
// block stalls at vmcnt/barrier, the other's waves feed the MFMA pipe.
// Phase body (r6 hybrid, unchanged): { ds_read(cur) ; stage(nxt) ; [VMCNT] ;
// s_barrier ; setprio(1) MFMA setprio(0) }.
// LDS: [row][64] bf16, phys 16B-slot = logical ^ (row&7). Staging: 256 thr x
// 16B = 32 rows per gload_lds call; chunk = 2 calls; vmcnt traces identical
// to r6 (same instrs/chunk).

// ---------------- GEMM1: h = silu(x@w1)*(x@w3) ------------------------------
// 128Mx64N dual-tensor, BK=64, 4 waves (2M x 2N), wave-tile 64x32 dual.
// Chunks: A0={rows 0-31,64-95} A1={32-63,96-127} B0=w1(64 rows) B1=w3.
// Phases: ph0:(acc1,mh0) reads A0,B0 | ph1:(acc3,mh0) reads B1 |
//         ph2:(acc1,mh1) reads A1   | ph3:(acc3,mh1) reads none.
// Stage t+1: A0@ph0 B0@ph1 B1@ph2 A1@ph3; steady vmcnt 4/4/-/4.
__global__ __launch_bounds__(256, 2) void gemm1_kernel(
    const unsigned short* __restrict__ xb,   // [T][D] bf16
    const unsigned short* __restrict__ w1t,  // [E][F][D] bf16
    const unsigned short* __restrict__ w3t,  // [E][F][D] bf16
    const int* __restrict__ rows,
    const int* __restrict__ hdr,
    unsigned short* __restrict__ h)          // [T*2][F] bf16 (slot space)
{
  const int e = blockIdx.z;
  const int count = hdr[e];
  const int m0 = blockIdx.y * 128;
  if (m0 >= count) return;
  const int n0 = blockIdx.x * 64;
  const int sbase = hdr[16 + e];

  __shared__ unsigned short As[2][8192];  // 128 x 64
  __shared__ unsigned short Bs[2][8192];  // [w1:64 | w3:64] x 64

  const int tid = threadIdx.x;
  const int srcoff = ((tid & 7) ^ ((tid >> 3) & 7)) * 8;
  const int rq = tid >> 3;  // 0..31
  const unsigned short* pA[4];
#pragma unroll
  for (int q = 0; q < 4; q++) {
    int m = m0 + q * 32 + rq; if (m > count - 1) m = count - 1;
    pA[q] = xb + (size_t)rows[sbase + m] * DDIM + srcoff;
  }
  const unsigned short* pB[4];
  pB[0] = w1t + ((size_t)e * FDIM + n0 + rq) * DDIM + srcoff;
  pB[1] = w1t + ((size_t)e * FDIM + n0 + 32 + rq) * DDIM + srcoff;
  pB[2] = w3t + ((size_t)e * FDIM + n0 + rq) * DDIM + srcoff;
  pB[3] = w3t + ((size_t)e * FDIM + n0 + 32 + rq) * DDIM + srcoff;
  const int l0 = tid * 8;

  const int wv = tid >> 6;          // 0..3
  const int wm = (wv >> 1) * 64;    // 0 / 64
  const int wn = (wv & 1) * 32;     // 0 / 32
  const int lane = tid & 63;
  const int lm = lane & 15;
  const int ls = lane >> 4;
  const int coff0 = ((ls) ^ (lm & 7)) * 8;
  const int coff1 = ((4 + ls) ^ (lm & 7)) * 8;

  f32x4 acc1[4][2], acc3[4][2];
#pragma unroll
  for (int i = 0; i < 4; i++)
#pragma unroll
    for (int j = 0; j < 2; j++) {
      acc1[i][j] = f32x4{0.f, 0.f, 0.f, 0.f};
      acc3[i][j] = f32x4{0.f, 0.f, 0.f, 0.f};
    }

  bf16x8 a[4], b1[4], b3[4];

  auto stageA0 = [&](int buf, int kt) {  // rows 0-31 (q0) + 64-95 (q2)
    async_cp16(pA[0] + kt, &As[buf][l0]);
    async_cp16(pA[2] + kt, &As[buf][4096 + l0]);
  };
  auto stageA1 = [&](int buf, int kt) {  // rows 32-63 (q1) + 96-127 (q3)
    async_cp16(pA[1] + kt, &As[buf][2048 + l0]);
    async_cp16(pA[3] + kt, &As[buf][6144 + l0]);
  };
  auto stageB0 = [&](int buf, int kt) {  // w1 rows 0-63
    async_cp16(pB[0] + kt, &Bs[buf][l0]);
    async_cp16(pB[1] + kt, &Bs[buf][2048 + l0]);
  };
  auto stageB1 = [&](int buf, int kt) {  // w3 rows 0-63 (at LDS rows 64-127)
    async_cp16(pB[2] + kt, &Bs[buf][4096 + l0]);
    async_cp16(pB[3] + kt, &Bs[buf][6144 + l0]);
  };
  auto rdA = [&](int cur, int mh) {
#pragma unroll
    for (int i = 0; i < 2; i++) {
      const unsigned short* rp = &As[cur][(wm + mh * 32 + i * 16 + lm) * 64];
      a[i * 2 + 0] = *(const bf16x8*)(rp + coff0);
      a[i * 2 + 1] = *(const bf16x8*)(rp + coff1);
    }
  };
  auto rdB = [&](int cur, int half, bf16x8* bb) {
#pragma unroll
    for (int j = 0; j < 2; j++) {
      const unsigned short* rp = &Bs[cur][(half * 64 + wn + j * 16 + lm) * 64];
      bb[j * 2 + 0] = *(const bf16x8*)(rp + coff0);
      bb[j * 2 + 1] = *(const bf16x8*)(rp + coff1);
    }
  };
  auto mm = [&](f32x4 (*acc)[2], int mh, bf16x8* bb) {
    __builtin_amdgcn_s_setprio(1);
#pragma unroll
    for (int i = 0; i < 2; i++)
#pragma unroll
      for (int j = 0; j < 2; j++) {
        f32x4 c = acc[mh * 2 + i][j];
        c = __builtin_amdgcn_mfma_f32_16x16x32_bf16(a[i * 2 + 0], bb[j * 2 + 0], c, 0, 0, 0);
        c = __builtin_amdgcn_mfma_f32_16x16x32_bf16(a[i * 2 + 1], bb[j * 2 + 1], c, 0, 0, 0);
        acc[mh * 2 + i][j] = c;
      }
    __builtin_amdgcn_s_setprio(0);
  };

  // prologue: stage tile 0; publish {A0,B0}(0)
  stageA0(0, 0); stageB0(0, 0); stageB1(0, 0); stageA1(0, 0);
  VMCNT(4); BAR();

  for (int t = 0; t < 15; ++t) {
    const int cur = t & 1, nxt = cur ^ 1;
    const int kt = (t + 1) * 64;
    // ph0: publish B1(t)
    rdA(cur, 0); rdB(cur, 0, b1); stageA0(nxt, kt); VMCNT(4); BAR();
    mm(acc1, 0, b1);
    // ph1: publish A1(t)
    rdB(cur, 1, b3); stageB0(nxt, kt); VMCNT(4); BAR();
    mm(acc3, 0, b3);
    // ph2: no publication
    rdA(cur, 1); stageB1(nxt, kt); BAR();
    mm(acc1, 1, b1);
    // ph3: publish {A0,B0}(t+1)
    stageA1(nxt, kt); VMCNT(4); BAR();
    mm(acc3, 1, b3);
  }
  {  // tail t=15 (cur=1), no staging; entry queue {B1,A1}=4
    rdA(1, 0); rdB(1, 0, b1); VMCNT(0); BAR();
    mm(acc1, 0, b1);
    rdB(1, 1, b3); mm(acc3, 0, b3);
    rdA(1, 1); mm(acc1, 1, b1);
    mm(acc3, 1, b3);
  }

#pragma unroll
  for (int i = 0; i < 4; i++) {
#pragma unroll
    for (int r = 0; r < 4; r++) {
      int mg = m0 + wm + i * 16 + ls * 4 + r;
      if (mg < count) {
        unsigned short* hp = h + (size_t)(sbase + mg) * FDIM + n0 + wn + lm;
#pragma unroll
        for (int j = 0; j < 2; j++) {
          float v1 = acc1[i][j][r];
          float v3 = acc3[i][j][r];
          float hv = (v1 / (1.0f + __expf(-v1))) * v3;
          hp[j * 16] = f2bf(hv);
        }
      }
    }
  }
}

// ---------------- GEMM2: y[slot] = h[slot] @ w2 ------------------------------
// 128Mx128N, BK=64, 4 waves (2M x 2N), wave-tile 64x64.
// Chunks: A0={0-31,64-95} A1={32-63,96-127} B0=rows 0-63 B1=rows 64-127.
// Phases (mh,kk): ph0 reads A0+B(kk0, both chunks) | ph1 A0+B(kk1) |
//                 ph2 A1 | ph3 A1. Stage t+1: B0,B1,A0,A1; vmcnt -/4/-/2.
__global__ __launch_bounds__(256, 2) void gemm2_kernel(
    const unsigned short* __restrict__ h,    // [T*2][F] bf16
    const unsigned short* __restrict__ w2t,  // [E][D][F] bf16
    const int* __restrict__ hdr,
    float* __restrict__ y)                   // [T*2][D] fp32 (slot space)
{
  const int e = blockIdx.z;
  const int count = hdr[e];
  const int m0 = blockIdx.y * 128;
  if (m0 >= count) return;
  const int n0 = blockIdx.x * 128;
  const int sbase = hdr[16 + e];

  __shared__ unsigned short As[2][8192];  // 128 x 64
  __shared__ unsigned short Bs[2][8192];  // 128 x 64

  const int tid = threadIdx.x;
  const int srcoff = ((tid & 7) ^ ((tid >> 3) & 7)) * 8;
  const int rq = tid >> 3;
  const unsigned short* pA[4];
#pragma unroll
  for (int q = 0; q < 4; q++) {
    int m = m0 + q * 32 + rq; if (m > count - 1) m = count - 1;
    pA[q] = h + (size_t)(sbase + m) * FDIM + srcoff;
  }
  const unsigned short* pB[4];
#pragma unroll
  for (int q = 0; q < 4; q++)
    pB[q] = w2t + ((size_t)e * DDIM + n0 + q * 32 + rq) * FDIM + srcoff;
  const int l0 = tid * 8;

  const int wv = tid >> 6;
  const int wm = (wv >> 1) * 64;
  const int wn = (wv & 1) * 64;
  const int lane = tid & 63;
  const int lm = lane & 15;
  const int ls = lane >> 4;
  const int coff0 = ((ls) ^ (lm & 7)) * 8;
  const int coff1 = ((4 + ls) ^ (lm & 7)) * 8;

  f32x4 acc[4][4];
#pragma unroll
  for (int i = 0; i < 4; i++)
#pragma unroll
    for (int j = 0; j < 4; j++) acc[i][j] = f32x4{0.f, 0.f, 0.f, 0.f};

  bf16x8 a[4], b[8];

  auto stageA0 = [&](int buf, int kt) {  // rows 0-31 (q0) + 64-95 (q2)
    async_cp16(pA[0] + kt, &As[buf][l0]);
    async_cp16(pA[2] + kt, &As[buf][4096 + l0]);
  };
  auto stageA1 = [&](int buf, int kt) {  // rows 32-63 (q1) + 96-127 (q3)
    async_cp16(pA[1] + kt, &As[buf][2048 + l0]);
    async_cp16(pA[3] + kt, &As[buf][6144 + l0]);
  };
  auto stageB0 = [&](int buf, int kt) {  // B rows 0-63
    async_cp16(pB[0] + kt, &Bs[buf][l0]);
    async_cp16(pB[1] + kt, &Bs[buf][2048 + l0]);
  };
  auto stageB1 = [&](int buf, int kt) {  // B rows 64-127
    async_cp16(pB[2] + kt, &Bs[buf][4096 + l0]);
    async_cp16(pB[3] + kt, &Bs[buf][6144 + l0]);
  };
  auto rdA2 = [&](int cur, int mh, int kk) {
#pragma unroll
    for (int i = 0; i < 2; i++) {
      const unsigned short* rp = &As[cur][(wm + mh * 32 + i * 16 + lm) * 64];
      a[kk * 2 + i] = *(const bf16x8*)(rp + (kk ? coff1 : coff0));
    }
  };
  auto rdB2 = [&](int cur, int kk) {
#pragma unroll
    for (int j = 0; j < 4; j++) {
      const unsigned short* rp = &Bs[cur][(wn + j * 16 + lm) * 64];
      b[kk * 4 + j] = *(const bf16x8*)(rp + (kk ? coff1 : coff0));
    }
  };
  auto mm2 = [&](int mh, int kk) {
    __builtin_amdgcn_s_setprio(1);
#pragma unroll
    for (int i = 0; i < 2; i++)
#pragma unroll
      for (int j = 0; j < 4; j++)
        acc[mh * 2 + i][j] =
            __builtin_amdgcn_mfma_f32_16x16x32_bf16(a[kk * 2 + i], b[kk * 4 + j],
                                                    acc[mh * 2 + i][j], 0, 0, 0);
    __builtin_amdgcn_s_setprio(0);
  };

  // prologue: stage tile 0; publish {B0,B1,A0}(0)
  stageB0(0, 0); stageB1(0, 0); stageA0(0, 0); stageA1(0, 0);
  VMCNT(2); BAR();

  for (int t = 0; t < 31; ++t) {
    const int cur = t & 1, nxt = cur ^ 1;
    const int kt = (t + 1) * 64;
    // ph0: no publication (inputs published at ph3(t-1))
    rdA2(cur, 0, 0); rdB2(cur, 0); stageB0(nxt, kt); BAR();
    mm2(0, 0);
    // ph1: publish A1(t)
    rdA2(cur, 0, 1); rdB2(cur, 1); stageB1(nxt, kt); VMCNT(4); BAR();
    mm2(0, 1);
    // ph2: no publication
    rdA2(cur, 1, 0); stageA0(nxt, kt); BAR();
    mm2(1, 0);
    // ph3: publish {B0,B1,A0}(t+1)
    rdA2(cur, 1, 1); stageA1(nxt, kt); VMCNT(2); BAR();
    mm2(1, 1);
  }
  {  // tail t=31 (cur=1), no staging; entry queue {A1}=2
    rdA2(1, 0, 0); rdB2(1, 0); VMCNT(0); BAR();
    mm2(0, 0);
    rdA2(1, 0, 1); rdB2(1, 1); mm2(0, 1);
    rdA2(1, 1, 0); mm2(1, 0);
    rdA2(1, 1, 1); mm2(1, 1);
  }

#pragma unroll
  for (int i = 0; i < 4; i++) {
#pragma unroll
    for (int r = 0; r < 4; r++) {
      int mg = m0 + wm + i * 16 + ls * 4 + r;
      if (mg < count) {
        float* yp = y + (size_t)(sbase + mg) * DDIM + n0 + wn + lm;
#pragma unroll
        for (int j = 0; j < 4; j++) yp[j * 16] = acc[i][j][r];
      }
    }
  }
}

// ---------------- combine: out[t] = p0*y[s0] + p1*y[s1] ----------------
__global__ __launch_bounds__(256) void combine_kernel(const float* __restrict__ y,
                                                      const int* __restrict__ slot_of,
                                                      const float* __restrict__ prb,
                                                      float* __restrict__ out) {
  int t = blockIdx.x;
  int s0 = slot_of[t * 2], s1 = slot_of[t * 2 + 1];
  float p0 = prb[t * 2], p1 = prb[t * 2 + 1];
  float4 a = ((const float4*)(y + (size_t)s0 * DDIM))[threadIdx.x];
  float4 b = ((const float4*)(y + (size_t)s1 * DDIM))[threadIdx.x];
  float4 o;
  o.x = p0 * a.x + p1 * b.x;
  o.y = p0 * a.y + p1 * b.y;
  o.z = p0 * a.z + p1 * b.z;
  o.w = p0 * a.w + p1 * b.w;
  ((float4*)(out + (size_t)t * DDIM))[threadIdx.x] = o;
}

extern "C" void kernel_launch(void* const* d_in, const int* in_sizes, int n_in,
                              void* d_out, int out_size, void* d_ws, size_t ws_size,
                              hipStream_t stream) {
  const float* x  = (const float*)d_in[0];
  const float* wg = (const float*)d_in[1];
  const float* w1 = (const float*)d_in[2];
  const float* w3 = (const float*)d_in[3];
  const float* w2 = (const float*)d_in[4];
  float* out = (float*)d_out;
  char* ws = (char*)d_ws;

  size_t off = 0;
  int* hdr = (int*)(ws + off); off += 256;
  int* sel = (int*)(ws + off); off += (size_t)T_TOK * 2 * 4;
  float* prb = (float*)(ws + off); off += (size_t)T_TOK * 2 * 4;
  int* rows = (int*)(ws + off); off += (size_t)T_TOK * 2 * 4;
  int* slot_of = (int*)(ws + off); off += (size_t)T_TOK * 2 * 4;
  int* cnt_blk = (int*)(ws + off); off += (size_t)GBLK * 8 * 4;
  int* blk_off = (int*)(ws + off); off += (size_t)GBLK * 8 * 4;
  unsigned short* xb  = (unsigned short*)(ws + off); off += (size_t)T_TOK * DDIM * 2;
  unsigned short* w1t = (unsigned short*)(ws + off); off += (size_t)EEXP * DDIM * FDIM * 2;
  unsigned short* w3t = (unsigned short*)(ws + off); off += (size_t)EEXP * DDIM * FDIM * 2;
  unsigned short* w2t = (unsigned short*)(ws + off); off += (size_t)EEXP * DDIM * FDIM * 2;
  unsigned short* h   = (unsigned short*)(ws + off); off += (size_t)T_TOK * 2 * FDIM * 2;
  // y overlays w1t+w3t (64 MB, dead after gemm1): [T*2][D] fp32
  float* y = (float*)w1t;

  gate_kernel<<<GBLK, 256, 0, stream>>>(x, wg, xb, sel, prb, cnt_blk);
  transpose_cast3_kernel<<<dim3(32, 32, 24), 256, 0, stream>>>(w1, w3, w2, w1t, w3t, w2t);
  scan_kernel<<<1, 64, 0, stream>>>(cnt_blk, hdr, blk_off);
  build_kernel<<<T_TOK * 2 / 64, 64, 0, stream>>>(sel, blk_off, rows, slot_of);
  gemm1_kernel<<<dim3(FDIM / 64, T_TOK / 128, EEXP), 256, 0, stream>>>(xb, w1t, w3t, rows, hdr, h);
  gemm2_kernel<<<dim3(DDIM / 128, T_TOK / 128, EEXP), 256, 0, stream>>>(h, w2t, hdr, y);
  combine_kernel<<<T_TOK, 256, 0, stream>>>(y, slot_of, prb, out);
}